// Round 12
// baseline (236.551 us; speedup 1.0000x reference)
//
#include <hip/hip_runtime.h>

// GCN 2-layer, deterministic sort + LDS aggregation (gfx950).
// History: global fp32 atomics are EA write-through -> eliminated (r5);
// cursor scatter raced on replay (r6/r8) -> deterministic partition sort (r9);
// LDS-reorder scatter + fusions (r10, 274us); SPLIT=4 bucket passes (r11,
// 226us). r11 lesson: occupancy 24->60% but aggp only 89->78us, VGPR_Count=4
// -> the compiler serialized the gather chain; latency-bound on per-thread
// MLP, not wave count. Round-12: explicit 8-deep staging in the edge passes
// (8 coalesced index loads -> 8 independent feat gathers in flight -> 16 LDS
// atomics), forcing memory-level parallelism with registers.

typedef unsigned int u32;
typedef unsigned short u16;

#define BUCKET_BITS 9
#define BUCKET_SIZE (1 << BUCKET_BITS)   // 512 nodes per bucket
#define MAX_NBUCK 512                    // supports N <= 262144
#define PCHUNK 8192                      // edges per partition chunk
#define STHREADS 512
#define MAX_NB 1024                      // supports E <= 8.4M
#define SPLIT 4                          // split-blocks per bucket edge pass
#define BATCH 8                          // staged edges per thread per batch

// K1: per-chunk bucket histogram -> part[c*nbuck + j]  (no global atomics)
__global__ void part_hist_kernel(const int* __restrict__ dst, u32* __restrict__ part,
                                 int E, int nbuck) {
    __shared__ u32 h[MAX_NBUCK];
    int t = threadIdx.x, c = blockIdx.x;
    h[t] = 0;
    __syncthreads();
    int start = c * PCHUNK, end = min(start + PCHUNK, E);
    for (int i = start + t; i < end; i += STHREADS)
        atomicAdd(&h[((u32)dst[i]) >> BUCKET_BITS], 1u);
    __syncthreads();
    for (int j = t; j < nbuck; j += STHREADS)
        part[(size_t)c * nbuck + j] = h[j];
}

// K2: per-bucket exclusive prefix across chunks (in place); totals -> cnt[j]
__global__ void colscan_kernel(u32* __restrict__ part, u32* __restrict__ cnt,
                               int NB, int nbuck) {
    __shared__ u32 s[MAX_NB];
    int t = threadIdx.x, j = blockIdx.x;  // 1024 threads, j < nbuck
    u32 v = (t < NB) ? part[(size_t)t * nbuck + j] : 0u;
    s[t] = v;
    for (int o = 1; o < MAX_NB; o <<= 1) {
        __syncthreads();
        u32 u = (t >= o) ? s[t - o] : 0u;
        __syncthreads();
        s[t] += u;
    }
    __syncthreads();
    if (t < NB) part[(size_t)t * nbuck + j] = s[t] - v;  // exclusive prefix
    if (t == MAX_NB - 1) cnt[j] = s[MAX_NB - 1];         // bucket total
}

// K3: exclusive scan of bucket totals -> offsets[0..nbuck]
__global__ void offsets_kernel(const u32* __restrict__ cnt, u32* __restrict__ offsets,
                               int nbuck) {
    __shared__ u32 s[MAX_NBUCK];
    int t = threadIdx.x;  // 512
    u32 v = (t < nbuck) ? cnt[t] : 0u;
    s[t] = v;
    for (int o = 1; o < MAX_NBUCK; o <<= 1) {
        __syncthreads();
        u32 u = (t >= o) ? s[t - o] : 0u;
        __syncthreads();
        s[t] += u;
    }
    __syncthreads();
    if (t < nbuck) offsets[t + 1] = s[t];
    if (t == 0) offsets[0] = 0;
}

// K4: LDS-reorder scatter, precomputed bases (replay-proven in r10)
__global__ void __launch_bounds__(STHREADS)
scatter_kernel(const int* __restrict__ src, const int* __restrict__ dst,
               const u32* __restrict__ part, const u32* __restrict__ offsets,
               u32* __restrict__ sorted, int E, int nbuck) {
    __shared__ u32 pk[PCHUNK];
    __shared__ u16 bk[PCHUNK];
    __shared__ u32 hist[MAX_NBUCK];
    __shared__ u32 scr[MAX_NBUCK];
    __shared__ u32 dadj[MAX_NBUCK];
    int t = threadIdx.x, c = blockIdx.x;
    int start = c * PCHUNK, end = min(start + PCHUNK, E);
    int cntE = end - start;

    hist[t] = 0;
    __syncthreads();
    for (int i = start + t; i < end; i += STHREADS)
        atomicAdd(&hist[((u32)dst[i]) >> BUCKET_BITS], 1u);
    __syncthreads();
    u32 v = hist[t];
    scr[t] = v;
    for (int o = 1; o < MAX_NBUCK; o <<= 1) {
        __syncthreads();
        u32 u = (t >= o) ? scr[t - o] : 0u;
        __syncthreads();
        scr[t] += u;
    }
    __syncthreads();
    u32 lb = scr[t] - v;
    hist[t] = lb;
    if (t < nbuck)
        dadj[t] = offsets[t] + part[(size_t)c * nbuck + t] - lb;
    scr[t] = 0;
    __syncthreads();
    for (int i = start + t; i < end; i += STHREADS) {
        u32 d = (u32)dst[i];
        u32 b = d >> BUCKET_BITS;
        u32 p = hist[b] + atomicAdd(&scr[b], 1u);
        pk[p] = ((u32)src[i] << BUCKET_BITS) | (d & (BUCKET_SIZE - 1));
        bk[p] = (u16)b;
    }
    __syncthreads();
    for (int i = t; i < cntE; i += STHREADS)
        sorted[dadj[bk[i]] + i] = pk[i];
}

// K5: split degree count -> pdeg[block][t]  (streaming, 8x unrolled)
__global__ void deg_part_kernel(const u32* __restrict__ sorted, const u32* __restrict__ offsets,
                                u32* __restrict__ pdeg) {
    __shared__ u32 cnt_s[BUCKET_SIZE];
    int t = threadIdx.x;
    int b = blockIdx.x / SPLIT, s = blockIdx.x % SPLIT;
    cnt_s[t] = 0;
    __syncthreads();
    u32 e0 = offsets[b], len = offsets[b + 1] - e0;
    u32 lo = e0 + (len * s) / SPLIT, hi = e0 + (len * (s + 1)) / SPLIT;
    for (u32 base = lo; base < hi; base += BATCH * BUCKET_SIZE) {
        u32 e[BATCH];
#pragma unroll
        for (int k = 0; k < BATCH; ++k) {
            u32 i = base + (u32)k * BUCKET_SIZE + t;
            e[k] = (i < hi) ? sorted[i] : 0xFFFFFFFFu;
        }
#pragma unroll
        for (int k = 0; k < BATCH; ++k)
            if (e[k] != 0xFFFFFFFFu)
                atomicAdd(&cnt_s[e[k] & (BUCKET_SIZE - 1)], 1u);
    }
    __syncthreads();
    pdeg[(size_t)blockIdx.x * BUCKET_SIZE + t] = cnt_s[t];
}

// K6: combine degree partials; dinv = rsqrt(deg+1); y = dinv * x
__global__ void dinv_y_kernel(const u32* __restrict__ pdeg, const float2* __restrict__ x,
                              float* __restrict__ dinv, float2* __restrict__ y, int N) {
    int b = blockIdx.x, t = threadIdx.x;
    int node = (b << BUCKET_BITS) + t;
    if (node >= N) return;
    u32 d = 0;
#pragma unroll
    for (int s = 0; s < SPLIT; ++s)
        d += pdeg[((size_t)(b * SPLIT + s)) * BUCKET_SIZE + t];
    float di = rsqrtf((float)d + 1.0f);  // +1 self-loop, always > 0
    dinv[node] = di;
    float2 xv = x[node];
    y[node] = make_float2(di * xv.x, di * xv.y);
}

// K7 (used twice): split aggregation with explicit 8-deep gather staging.
// Phase 1: 8 coalesced index loads; Phase 2: 8 INDEPENDENT feat gathers
// (all in flight under one vmcnt window); Phase 3: 16 LDS atomics.
__global__ void aggp_kernel(const u32* __restrict__ sorted, const u32* __restrict__ offsets,
                            const float2* __restrict__ feat, float2* __restrict__ pagg) {
    __shared__ float accx[BUCKET_SIZE];
    __shared__ float accy[BUCKET_SIZE];
    int t = threadIdx.x;
    int b = blockIdx.x / SPLIT, s = blockIdx.x % SPLIT;
    accx[t] = 0.f;
    accy[t] = 0.f;
    __syncthreads();
    u32 e0 = offsets[b], len = offsets[b + 1] - e0;
    u32 lo = e0 + (len * s) / SPLIT, hi = e0 + (len * (s + 1)) / SPLIT;
    for (u32 base = lo; base < hi; base += BATCH * BUCKET_SIZE) {
        u32 e[BATCH];
        float vx[BATCH], vy[BATCH];
#pragma unroll
        for (int k = 0; k < BATCH; ++k) {
            u32 i = base + (u32)k * BUCKET_SIZE + t;
            e[k] = (i < hi) ? sorted[i] : 0xFFFFFFFFu;
        }
#pragma unroll
        for (int k = 0; k < BATCH; ++k) {
            if (e[k] != 0xFFFFFFFFu) {
                float2 v = feat[e[k] >> BUCKET_BITS];
                vx[k] = v.x; vy[k] = v.y;
            } else {
                vx[k] = 0.f; vy[k] = 0.f;
            }
        }
#pragma unroll
        for (int k = 0; k < BATCH; ++k) {
            if (e[k] != 0xFFFFFFFFu) {
                u32 ld = e[k] & (BUCKET_SIZE - 1);
                atomicAdd(&accx[ld], vx[k]);
                atomicAdd(&accy[ld], vy[k]);
            }
        }
    }
    __syncthreads();
    pagg[(size_t)blockIdx.x * BUCKET_SIZE + t] = make_float2(accx[t], accy[t]);
}

// K8: combine layer-1 partials + self-loop, then fused 2->16->2 MLP
__global__ void mlp_combine_kernel(const float2* __restrict__ pagg, const float2* __restrict__ y,
                                   const float* __restrict__ dinv,
                                   const float* __restrict__ W1, const float* __restrict__ b1,
                                   const float* __restrict__ W2,
                                   float2* __restrict__ gp, int N) {
    int b = blockIdx.x, t = threadIdx.x;
    int node = (b << BUCKET_BITS) + t;
    if (node >= N) return;
    float sx = 0.f, sy = 0.f;
#pragma unroll
    for (int s = 0; s < SPLIT; ++s) {
        float2 p = pagg[((size_t)(b * SPLIT + s)) * BUCKET_SIZE + t];
        sx += p.x; sy += p.y;
    }
    float di = dinv[node];
    float2 yv = y[node];
    float ax = di * (sx + yv.x);
    float ay = di * (sy + yv.y);
    float g0 = 0.f, g1 = 0.f;
#pragma unroll
    for (int j = 0; j < 16; ++j) {
        float h = fmaf(ax, W1[j], fmaf(ay, W1[16 + j], b1[j]));
        h = fmaxf(h, 0.f);
        g0 = fmaf(h, W2[2 * j], g0);
        g1 = fmaf(h, W2[2 * j + 1], g1);
    }
    gp[node] = make_float2(di * g0, di * g1);
}

// K9: combine layer-2 partials + self-loop + bias -> out
__global__ void final_combine_kernel(const float2* __restrict__ pagg, const float2* __restrict__ gp,
                                     const float* __restrict__ dinv, const float* __restrict__ b2,
                                     float2* __restrict__ out, int N) {
    int b = blockIdx.x, t = threadIdx.x;
    int node = (b << BUCKET_BITS) + t;
    if (node >= N) return;
    float sx = 0.f, sy = 0.f;
#pragma unroll
    for (int s = 0; s < SPLIT; ++s) {
        float2 p = pagg[((size_t)(b * SPLIT + s)) * BUCKET_SIZE + t];
        sx += p.x; sy += p.y;
    }
    float di = dinv[node];
    float2 gv = gp[node];
    out[node] = make_float2(fmaf(di, sx + gv.x, b2[0]),
                            fmaf(di, sy + gv.y, b2[1]));
}

extern "C" void kernel_launch(void* const* d_in, const int* in_sizes, int n_in,
                              void* d_out, int out_size, void* d_ws, size_t ws_size,
                              hipStream_t stream) {
    const float2* x  = (const float2*)d_in[0];
    const int*    ei = (const int*)d_in[1];   // [2, E]: src row then dst row
    const float*  W1 = (const float*)d_in[2];
    const float*  b1 = (const float*)d_in[3];
    const float*  W2 = (const float*)d_in[4];
    const float*  b2 = (const float*)d_in[5];

    const int N = in_sizes[0] / 2;
    const int E = in_sizes[1] / 2;
    const int* src = ei;
    const int* dst = ei + E;
    const int nbuck = (N + BUCKET_SIZE - 1) >> BUCKET_BITS;   // 391
    const int NB    = (E + PCHUNK - 1) / PCHUNK;              // 782 (<= 1024)

    // Workspace (lifetime-ordered aliases, all pure functions of inputs):
    //   part  (NB*nbuck u32, ~1.2MB) aliases y  : dead before deg_y writes y
    //   pdeg  (nbuck*SPLIT*512 u32)  aliases pagg: dead before aggp writes pagg
    //   pagg reused by both agg passes (combine1 reads before agg2 rewrites)
    u32* sorted   = (u32*)d_ws;                               // E
    float* dinv   = (float*)(sorted + E);                     // N
    float* y      = dinv + N;                                 // 2N
    float* gp     = y + 2 * (size_t)N;                        // 2N
    float2* pagg  = (float2*)(gp + 2 * (size_t)N);            // nbuck*SPLIT*512
    u32* pdeg     = (u32*)pagg;                               // alias (half size)
    u32* cnt      = (u32*)(pagg + (size_t)nbuck * SPLIT * BUCKET_SIZE); // 512
    u32* offsets  = cnt + MAX_NBUCK;                          // nbuck+1
    u32* part     = (u32*)y;                                  // alias
    float2* out   = (float2*)d_out;

    part_hist_kernel  <<<NB, STHREADS, 0, stream>>>(dst, part, E, nbuck);
    colscan_kernel    <<<nbuck, MAX_NB, 0, stream>>>(part, cnt, NB, nbuck);
    offsets_kernel    <<<1, MAX_NBUCK, 0, stream>>>(cnt, offsets, nbuck);
    scatter_kernel    <<<NB, STHREADS, 0, stream>>>(src, dst, part, offsets, sorted, E, nbuck);
    deg_part_kernel   <<<nbuck * SPLIT, BUCKET_SIZE, 0, stream>>>(sorted, offsets, pdeg);
    dinv_y_kernel     <<<nbuck, BUCKET_SIZE, 0, stream>>>(pdeg, x, dinv, (float2*)y, N);
    aggp_kernel       <<<nbuck * SPLIT, BUCKET_SIZE, 0, stream>>>(sorted, offsets,
                                                                  (const float2*)y, pagg);
    mlp_combine_kernel<<<nbuck, BUCKET_SIZE, 0, stream>>>(pagg, (const float2*)y, dinv,
                                                          W1, b1, W2, (float2*)gp, N);
    aggp_kernel       <<<nbuck * SPLIT, BUCKET_SIZE, 0, stream>>>(sorted, offsets,
                                                                  (const float2*)gp, pagg);
    final_combine_kernel<<<nbuck, BUCKET_SIZE, 0, stream>>>(pagg, (const float2*)gp, dinv,
                                                            b2, out, N);
}